// Round 4
// baseline (7677.631 us; speedup 1.0000x reference)
//
#include <hip/hip_runtime.h>

#define NPTS 8192
#define HDIM 64
#define KNN 16
#define LOG2E 1.4426950408889634f

typedef __attribute__((ext_vector_type(8))) short bf8_t;   // 8 bf16
typedef __attribute__((ext_vector_type(4))) float f4_t;    // MFMA C/D
#define MFMA16(a, b, c) __builtin_amdgcn_mfma_f32_16x16x32_bf16(a, b, c, 0, 0, 0)

__device__ __forceinline__ float fast_exp(float x) {
    float y = x * LOG2E;
    float r;
    asm volatile("v_exp_f32 %0, %1\n\ts_nop 1" : "=v"(r) : "v"(y));
    return r;
}
__device__ __forceinline__ unsigned short f2b(float x) {   // f32 -> bf16 RNE
    unsigned v = __float_as_uint(x);
    return (unsigned short)((v + 0x7FFFu + ((v >> 16) & 1u)) >> 16);
}

// ws layout: qw 0..4MB, kw 4..8MB, vw 8..12MB, frag 12MB..+24KB, knnIdx +32KB..+1MB
#define OFF_QW   0u
#define OFF_KW   (4u << 20)
#define OFF_VW   (8u << 20)
#define OFF_FRAG (12u << 20)
#define OFF_KNN  ((12u << 20) + 32768u)     // ws >= 14.8 MB (established R12)

// ---------------------------------------------------------------------------
// prefrag: pack Wp2/Wt1/Wt2 into MFMA B-frag order (proven R11-R15).
// ---------------------------------------------------------------------------
__global__ void prefrag_kernel(const float* __restrict__ Wp2,
                               const float* __restrict__ Wt1,
                               const float* __restrict__ Wt2,
                               unsigned short* __restrict__ dst)
{
    int i = blockIdx.x * 256 + threadIdx.x;
    if (i >= 3 * 4096) return;
    int st = i >> 12, e = i & 4095;
    const float* W = (st == 0) ? Wp2 : (st == 1) ? Wt1 : Wt2;
    int k = e >> 6, n = e & 63;
    int s = k >> 5, quad = (k >> 3) & 3, j = k & 7;
    int t = n >> 4, l = quad * 16 + (n & 15);
    dst[st * 4096 + (s * 4 + t) * 512 + l * 8 + j] = f2b(W[e]);
}

// ---------------------------------------------------------------------------
// proj v2: LDS-staged weights (proven R14+). Inner math f32, bit-identical.
// ---------------------------------------------------------------------------
__global__ __launch_bounds__(1024) void proj_kernel(
    const float* __restrict__ feat,
    const float* __restrict__ Wk, const float* __restrict__ bk,
    const float* __restrict__ Wq, const float* __restrict__ Wks,
    const float* __restrict__ Wv,
    float* __restrict__ qw, float* __restrict__ kw, float* __restrict__ vw)
{
    __shared__ __align__(16) float4 sW[4][1024];   // Wk, Wq, Wks, Wv (64 KB)
    int tid = threadIdx.x;
    sW[0][tid] = ((const float4*)Wk)[tid];
    sW[1][tid] = ((const float4*)Wq)[tid];
    sW[2][tid] = ((const float4*)Wks)[tid];
    sW[3][tid] = ((const float4*)Wv)[tid];
    __syncthreads();
    const float* sWk  = (const float*)sW[0];
    const float* sWq  = (const float*)sW[1];
    const float* sWks = (const float*)sW[2];
    const float* sWv  = (const float*)sW[3];

    int w = tid >> 6, lane = tid & 63;
    int p = blockIdx.x * 16 + w;
    float f = feat[(size_t)p * HDIM + lane];
    float x = bk[lane];
    #pragma unroll 8
    for (int c = 0; c < 64; ++c) x += __shfl(f, c) * sWk[c * 64 + lane];
    float q = 0.f, k = 0.f, v = 0.f;
    #pragma unroll 8
    for (int c = 0; c < 64; ++c) {
        float xc = __shfl(x, c);
        q += xc * sWq[c * 64 + lane];
        k += xc * sWks[c * 64 + lane];
        v += xc * sWv[c * 64 + lane];
    }
    qw[(size_t)p * HDIM + lane] = q;
    kw[(size_t)p * HDIM + lane] = k;
    vw[(size_t)p * HDIM + lane] = v;
}

// ---------------------------------------------------------------------------
// knn v6: half-scan wave split (occupancy 2x), exact merge.
// R18 post-mortem: knn is LATENCY-bound, not issue-bound — 258 cy/qi-unit vs
// ~50 issue cy at only 4 waves/SIMD (grid 1024 blocks). Instruction-count
// changes (R16/R17/R18) never moved duration. Fix the wave count:
// each query-quad's scan splits into two 4096-candidate halves on two waves
// -> grid 2048 blocks = 32 waves/CU (8/SIMD). Each wave computes the EXACT
// top-16 of its half (same top-4/lane + tau-guard + head>=4 exact repair,
// ranges restricted to the half; machinery proven R18). Global top-16 is a
// subset of the two half-top-16s; merge 32->16 by (d, lower idx) with the
// existing shfl-reduce/knockout pattern (indices disjoint across halves) —
// exact, same tie order as reference top_k. Prefetch dropped (TLP replaces
// it) to keep VGPR <= 64 for 8 waves/SIMD residency.
// ---------------------------------------------------------------------------
__global__ __launch_bounds__(256, 8) void knnh_kernel(
    const float* __restrict__ xyzp, int* __restrict__ knnIdx)
{
    __shared__ float sD[2][2][4][16];   // [quad-in-block][half][qi][r]
    __shared__ int   sI[2][2][4][16];

    int w = threadIdx.x >> 6, lane = threadIdx.x & 63;
    int qsel = w >> 1, half = w & 1;
    int wid = blockIdx.x * 2 + qsel;     // quad id 0..4095
    int pbase = wid * 4;                 // 4 consecutive points, same batch
    int b = pbase >> 13;
    int nbase = pbase & (NPTS - 1);
    const float4* xb4 = (const float4*)xyzp + (size_t)b * NPTS;
    int cbase = half * (NPTS / 2);       // this wave's candidate half

    float qx[4], qy[4], qz[4], qs[4];
    #pragma unroll
    for (int qi = 0; qi < 4; ++qi) {
        float4 s = xb4[nbase + qi];
        qx[qi] = s.x; qy[qi] = s.y; qz[qi] = s.z;
        qs[qi] = s.x * s.x + s.y * s.y + s.z * s.z;
    }

    float dh[4][4]; int ih[4][4];
    #pragma unroll
    for (int qi = 0; qi < 4; ++qi)
        #pragma unroll
        for (int j = 0; j < 4; ++j) { dh[qi][j] = 3.4e38f; ih[qi][j] = 0x7fffffff; }

    float tau[4];
    #pragma unroll
    for (int qi = 0; qi < 4; ++qi) tau[qi] = 3.4e38f;

    #pragma unroll 1
    for (int t = 0; t < NPTS / 512; ++t) {          // 16 iters x 256 cands
        float4 c[4];
        #pragma unroll
        for (int u = 0; u < 4; ++u)
            c[u] = xb4[cbase + (t * 4 + u) * 64 + lane];
        #pragma unroll
        for (int u = 0; u < 4; ++u) {
            int m = cbase + (t * 4 + u) * 64 + lane;
            float cs = c[u].x * c[u].x + c[u].y * c[u].y + c[u].z * c[u].z;
            #pragma unroll
            for (int qi = 0; qi < 4; ++qi) {
                float d = qs[qi] + cs
                        - 2.0f * (qx[qi] * c[u].x + qy[qi] * c[u].y + qz[qi] * c[u].z);
                if (__any(d <= tau[qi])) {
                    bool c3 = d < dh[qi][3];
                    bool c2 = d < dh[qi][2];
                    bool c1 = d < dh[qi][1];
                    bool c0 = d < dh[qi][0];
                    dh[qi][3] = c2 ? dh[qi][2] : (c3 ? d : dh[qi][3]);
                    ih[qi][3] = c2 ? ih[qi][2] : (c3 ? m : ih[qi][3]);
                    dh[qi][2] = c1 ? dh[qi][1] : (c2 ? d : dh[qi][2]);
                    ih[qi][2] = c1 ? ih[qi][1] : (c2 ? m : ih[qi][2]);
                    dh[qi][1] = c0 ? dh[qi][0] : (c1 ? d : dh[qi][1]);
                    ih[qi][1] = c0 ? ih[qi][0] : (c1 ? m : ih[qi][1]);
                    dh[qi][0] = c0 ? d : dh[qi][0];
                    ih[qi][0] = c0 ? m : ih[qi][0];
                }
            }
        }
        if (t & 1) {
            // tau = max over 4 groups-of-16 of (min over group of dh[3]):
            // upper bound on this half's 16th-best (proven R18)
            #pragma unroll
            for (int qi = 0; qi < 4; ++qi) {
                float t4 = dh[qi][3];
                t4 = fminf(t4, __shfl_xor(t4, 1));
                t4 = fminf(t4, __shfl_xor(t4, 2));
                t4 = fminf(t4, __shfl_xor(t4, 4));
                t4 = fminf(t4, __shfl_xor(t4, 8));
                t4 = fmaxf(t4, __shfl_xor(t4, 16));
                t4 = fmaxf(t4, __shfl_xor(t4, 32));
                tau[qi] = t4;
            }
        }
    }

    // per-qi: exact half-top-16 extraction (+ repair over own half), to LDS
    #pragma unroll 1
    for (int qi = 0; qi < 4; ++qi) {
        float mynd = 3.4e38f; int mynb = 0x7fffffff; int head = 0;
        #pragma unroll 1
        for (int r = 0; r < KNN; ++r) {
            float d = dh[qi][0]; int i = ih[qi][0];
            #pragma unroll
            for (int s = 1; s < 64; s <<= 1) {
                float d2 = __shfl_xor(d, s); int i2 = __shfl_xor(i, s);
                if (d2 < d || (d2 == d && i2 < i)) { d = d2; i = i2; }
            }
            if (lane == r) { mynb = i; mynd = d; }
            if (ih[qi][0] == i) {
                dh[qi][0] = dh[qi][1]; ih[qi][0] = ih[qi][1];
                dh[qi][1] = dh[qi][2]; ih[qi][1] = ih[qi][2];
                dh[qi][2] = dh[qi][3]; ih[qi][2] = ih[qi][3];
                dh[qi][3] = 3.4e38f; ih[qi][3] = 0x7fffffff;
                ++head;
            }
        }
        // exact repair over own half (proven pattern, range-restricted)
        if (__any(head >= 4)) {
            float eh[16]; int ei[16];
            #pragma unroll
            for (int j = 0; j < 16; ++j) { eh[j] = 3.4e38f; ei[j] = 0x7fffffff; }
            for (int t = 0; t < (NPTS / 2) / 64; ++t) {
                int m = cbase + t * 64 + lane;
                float4 c4 = xb4[m];
                float cs = c4.x * c4.x + c4.y * c4.y + c4.z * c4.z;
                float d = qs[qi] + cs
                        - 2.0f * (qx[qi] * c4.x + qy[qi] * c4.y + qz[qi] * c4.z);
                if (d < eh[15]) {
                    eh[15] = d; ei[15] = m;
                    #pragma unroll
                    for (int j = 15; j >= 1; --j)
                        if (eh[j] < eh[j - 1]) {
                            float td = eh[j]; eh[j] = eh[j - 1]; eh[j - 1] = td;
                            int ti = ei[j]; ei[j] = ei[j - 1]; ei[j - 1] = ti;
                        }
                }
            }
            #pragma unroll 1
            for (int r = 0; r < KNN; ++r) {
                float d = eh[0]; int i = ei[0];
                #pragma unroll
                for (int s = 1; s < 64; s <<= 1) {
                    float d2 = __shfl_xor(d, s); int i2 = __shfl_xor(i, s);
                    if (d2 < d || (d2 == d && i2 < i)) { d = d2; i = i2; }
                }
                if (lane == r) { mynb = i; mynd = d; }
                if (ei[0] == i) {
                    #pragma unroll
                    for (int j = 0; j < 15; ++j) { eh[j] = eh[j + 1]; ei[j] = ei[j + 1]; }
                    eh[15] = 3.4e38f; ei[15] = 0x7fffffff;
                }
            }
        }
        if (lane < KNN) {
            sD[qsel][half][qi][lane] = mynd;
            sI[qsel][half][qi][lane] = mynb;
        }
    }
    __syncthreads();

    // merge 16+16 -> 16 per qi (indices disjoint across halves -> knockout
    // by index is unambiguous); half-0 wave writes
    #pragma unroll 1
    for (int qi = 0; qi < 4; ++qi) {
        float d = 3.4e38f; int idx = 0x7fffffff;
        if (lane < 32) {
            d   = sD[qsel][lane >> 4][qi][lane & 15];
            idx = sI[qsel][lane >> 4][qi][lane & 15];
        }
        int outv = 0;
        #pragma unroll 1
        for (int r = 0; r < KNN; ++r) {
            float dm = d; int im = idx;
            #pragma unroll
            for (int s = 1; s < 64; s <<= 1) {
                float d2 = __shfl_xor(dm, s); int i2 = __shfl_xor(im, s);
                if (d2 < dm || (d2 == dm && i2 < im)) { dm = d2; im = i2; }
            }
            if (lane == r) outv = im;
            if (idx == im) d = 3.4e38f;
        }
        outv = min(max(outv, 0), NPTS - 1);
        if (half == 0 && lane < KNN)
            knnIdx[(size_t)(pbase + qi) * KNN + lane] = outv;
    }
}

// ---------------------------------------------------------------------------
// main: MFMA per-neighbor MLPs consuming knnIdx (proven verbatim R12/R14/R15).
// ---------------------------------------------------------------------------
__global__ __launch_bounds__(256) void LocalTransformer_80513456931527_kernel(
    const float* __restrict__ xyzp, const float* __restrict__ features,
    const float* __restrict__ Wp1,  const float* __restrict__ bp1,
    const float* __restrict__ bp2,  const float* __restrict__ bt1,
    const float* __restrict__ bt2,
    const float* __restrict__ Wa,   const float* __restrict__ ba,
    const float* __restrict__ qw, const float* __restrict__ kw,
    const float* __restrict__ vw,
    const unsigned short* __restrict__ fragw,
    const int* __restrict__ knnIdx,
    float* __restrict__ out)
{
    __shared__ __align__(16) float sBounce[4][16 * 68 + 4];

    int tid = threadIdx.x, w = tid >> 6, lane = tid & 63;
    int p = blockIdx.x * 4 + w;
    int b = p >> 13;
    float* bb = sBounce[w];

    int quad = lane >> 4, l15 = lane & 15;
    int mynb = knnIdx[(size_t)p * KNN + l15];
    mynb = min(max(mynb, 0), NPTS - 1);
    int nb_a = mynb;
    int nbm[4];
    #pragma unroll
    for (int r = 0; r < 4; ++r) nbm[r] = __shfl(mynb, quad * 4 + r);

    const float4 xq4 = *(const float4*)(xyzp + (size_t)p * 4);
    const float4 xn4 = *(const float4*)(xyzp + ((size_t)b * NPTS + nb_a) * 4);
    float rel0 = xq4.x - xn4.x, rel1 = xq4.y - xn4.y;
    float rel2 = xq4.z - xn4.z, rel3 = xq4.w - xn4.w;

    bf8_t pe1f[2];
    #pragma unroll
    for (int s = 0; s < 2; ++s) {
        int hb = s * 32 + quad * 8;
        float W0[8], W1[8], W2[8], W3[8], Bb[8];
        *(float4*)&W0[0] = *(const float4*)(Wp1 +       hb);
        *(float4*)&W0[4] = *(const float4*)(Wp1 +       hb + 4);
        *(float4*)&W1[0] = *(const float4*)(Wp1 +  64 + hb);
        *(float4*)&W1[4] = *(const float4*)(Wp1 +  64 + hb + 4);
        *(float4*)&W2[0] = *(const float4*)(Wp1 + 128 + hb);
        *(float4*)&W2[4] = *(const float4*)(Wp1 + 128 + hb + 4);
        *(float4*)&W3[0] = *(const float4*)(Wp1 + 192 + hb);
        *(float4*)&W3[4] = *(const float4*)(Wp1 + 192 + hb + 4);
        *(float4*)&Bb[0] = *(const float4*)(bp1 + hb);
        *(float4*)&Bb[4] = *(const float4*)(bp1 + hb + 4);
        #pragma unroll
        for (int j = 0; j < 8; ++j) {
            float a = Bb[j] + rel0 * W0[j] + rel1 * W1[j]
                            + rel2 * W2[j] + rel3 * W3[j];
            pe1f[s][j] = (short)f2b(fmaxf(a, 0.f));
        }
    }

    const bf8_t* BW = (const bf8_t*)fragw;
    f4_t pe2c[4];
    #pragma unroll
    for (int t = 0; t < 4; ++t) {
        f4_t acc = {0.f, 0.f, 0.f, 0.f};
        acc = MFMA16(pe1f[0], BW[0 * 512 + (0 * 4 + t) * 64 + lane], acc);
        acc = MFMA16(pe1f[1], BW[0 * 512 + (1 * 4 + t) * 64 + lane], acc);
        float bias = bp2[t * 16 + l15];
        #pragma unroll
        for (int r = 0; r < 4; ++r) acc[r] += bias;
        pe2c[t] = acc;
    }

    f4_t ainc[4], vpec[4];
    #pragma unroll
    for (int t = 0; t < 4; ++t) {
        float qv = qw[(size_t)p * HDIM + t * 16 + l15];
        #pragma unroll
        for (int r = 0; r < 4; ++r) {
            size_t nbo = ((size_t)b * NPTS + nbm[r]) * HDIM + t * 16 + l15;
            ainc[t][r] = qv - kw[nbo] + pe2c[t][r];
            vpec[t][r] = vw[nbo] + pe2c[t][r];
        }
    }

    #pragma unroll
    for (int t = 0; t < 4; ++t)
        #pragma unroll
        for (int r = 0; r < 4; ++r)
            bb[(quad * 4 + r) * 68 + t * 16 + l15] = ainc[t][r];
    asm volatile("s_waitcnt lgkmcnt(0)" ::: "memory");
    bf8_t af[2];
    #pragma unroll
    for (int s = 0; s < 2; ++s) {
        float tmp[8];
        *(float4*)&tmp[0] = *(const float4*)&bb[l15 * 68 + s * 32 + quad * 8];
        *(float4*)&tmp[4] = *(const float4*)&bb[l15 * 68 + s * 32 + quad * 8 + 4];
        #pragma unroll
        for (int j = 0; j < 8; ++j) af[s][j] = (short)f2b(tmp[j]);
    }

    f4_t t1c[4];
    #pragma unroll
    for (int t = 0; t < 4; ++t) {
        f4_t acc = {0.f, 0.f, 0.f, 0.f};
        acc = MFMA16(af[0], BW[1 * 512 + (0 * 4 + t) * 64 + lane], acc);
        acc = MFMA16(af[1], BW[1 * 512 + (1 * 4 + t) * 64 + lane], acc);
        float bias = bt1[t * 16 + l15];
        #pragma unroll
        for (int r = 0; r < 4; ++r) t1c[t][r] = fmaxf(acc[r] + bias, 0.f);
    }

    asm volatile("s_waitcnt lgkmcnt(0)" ::: "memory");
    #pragma unroll
    for (int t = 0; t < 4; ++t)
        #pragma unroll
        for (int r = 0; r < 4; ++r)
            bb[(quad * 4 + r) * 68 + t * 16 + l15] = t1c[t][r];
    asm volatile("s_waitcnt lgkmcnt(0)" ::: "memory");
    bf8_t tf[2];
    #pragma unroll
    for (int s = 0; s < 2; ++s) {
        float tmp[8];
        *(float4*)&tmp[0] = *(const float4*)&bb[l15 * 68 + s * 32 + quad * 8];
        *(float4*)&tmp[4] = *(const float4*)&bb[l15 * 68 + s * 32 + quad * 8 + 4];
        #pragma unroll
        for (int j = 0; j < 8; ++j) tf[s][j] = (short)f2b(tmp[j]);
    }

    f4_t lgc[4];
    #pragma unroll
    for (int t = 0; t < 4; ++t) {
        f4_t acc = {0.f, 0.f, 0.f, 0.f};
        acc = MFMA16(tf[0], BW[2 * 512 + (0 * 4 + t) * 64 + lane], acc);
        acc = MFMA16(tf[1], BW[2 * 512 + (1 * 4 + t) * 64 + lane], acc);
        float bias = bt2[t * 16 + l15];
        #pragma unroll
        for (int r = 0; r < 4; ++r) lgc[t][r] = (acc[r] + bias) * 0.125f;
    }

    float res[4];
    #pragma unroll
    for (int t = 0; t < 4; ++t) {
        float m0 = fmaxf(fmaxf(lgc[t][0], lgc[t][1]), fmaxf(lgc[t][2], lgc[t][3]));
        m0 = fmaxf(m0, __shfl_xor(m0, 16));
        m0 = fmaxf(m0, __shfl_xor(m0, 32));
        float e0 = fast_exp(lgc[t][0] - m0), e1 = fast_exp(lgc[t][1] - m0);
        float e2 = fast_exp(lgc[t][2] - m0), e3 = fast_exp(lgc[t][3] - m0);
        float sl = e0 + e1 + e2 + e3;
        float rl = e0 * vpec[t][0] + e1 * vpec[t][1]
                 + e2 * vpec[t][2] + e3 * vpec[t][3];
        sl += __shfl_xor(sl, 16); sl += __shfl_xor(sl, 32);
        rl += __shfl_xor(rl, 16); rl += __shfl_xor(rl, 32);
        res[t] = rl / sl;
    }

    float rh = (quad == 0) ? res[0] : (quad == 1) ? res[1]
             : (quad == 2) ? res[2] : res[3];
    float f = features[(size_t)p * HDIM + lane];
    float o = ba[lane];
    #pragma unroll 8
    for (int c = 0; c < 64; ++c) o += __shfl(rh, c) * Wa[c * 64 + lane];
    out[(size_t)p * HDIM + lane] = o + f;
}

// ---------------------------------------------------------------------------
extern "C" void kernel_launch(void* const* d_in, const int* in_sizes, int n_in,
                              void* d_out, int out_size, void* d_ws, size_t ws_size,
                              hipStream_t stream)
{
    (void)in_sizes; (void)n_in; (void)out_size; (void)ws_size;
    const float* xyzp     = (const float*)d_in[0];
    const float* features = (const float*)d_in[1];
    const float* Wk  = (const float*)d_in[2];
    const float* bk  = (const float*)d_in[3];
    const float* Wq  = (const float*)d_in[4];
    const float* Wks = (const float*)d_in[5];
    const float* Wv  = (const float*)d_in[6];
    const float* Wp1 = (const float*)d_in[7];
    const float* bp1 = (const float*)d_in[8];
    const float* Wp2 = (const float*)d_in[9];
    const float* bp2 = (const float*)d_in[10];
    const float* Wt1 = (const float*)d_in[11];
    const float* bt1 = (const float*)d_in[12];
    const float* Wt2 = (const float*)d_in[13];
    const float* bt2 = (const float*)d_in[14];
    const float* Wa  = (const float*)d_in[15];
    const float* ba  = (const float*)d_in[16];
    float* out = (float*)d_out;
    char* ws = (char*)d_ws;

    float* qw = (float*)(ws + OFF_QW);
    float* kw = (float*)(ws + OFF_KW);
    float* vw = (float*)(ws + OFF_VW);
    unsigned short* fragw = (unsigned short*)(ws + OFF_FRAG);
    int* knnIdx = (int*)(ws + OFF_KNN);

    prefrag_kernel<<<48, 256, 0, stream>>>(Wp2, Wt1, Wt2, fragw);
    proj_kernel<<<(2 * NPTS) / 16, 1024, 0, stream>>>(
        features, Wk, bk, Wq, Wks, Wv, qw, kw, vw);
    knnh_kernel<<<(2 * NPTS) / 8, 256, 0, stream>>>(xyzp, knnIdx);
    LocalTransformer_80513456931527_kernel<<<(2 * NPTS) / 4, 256, 0, stream>>>(
        xyzp, features, Wp1, bp1, bp2, bt1, bt2, Wa, ba,
        qw, kw, vw, fragw, knnIdx, out);
}

// Round 5
// 814.366 us; speedup vs baseline: 9.4277x; 9.4277x over previous
//
#include <hip/hip_runtime.h>

#define NPTS 8192
#define HDIM 64
#define KNN 16
#define LOG2E 1.4426950408889634f

typedef __attribute__((ext_vector_type(8))) short bf8_t;   // 8 bf16
typedef __attribute__((ext_vector_type(4))) float f4_t;    // MFMA C/D
#define MFMA16(a, b, c) __builtin_amdgcn_mfma_f32_16x16x32_bf16(a, b, c, 0, 0, 0)

__device__ __forceinline__ float fast_exp(float x) {
    float y = x * LOG2E;
    float r;
    asm volatile("v_exp_f32 %0, %1\n\ts_nop 1" : "=v"(r) : "v"(y));
    return r;
}
__device__ __forceinline__ unsigned short f2b(float x) {   // f32 -> bf16 RNE
    unsigned v = __float_as_uint(x);
    return (unsigned short)((v + 0x7FFFu + ((v >> 16) & 1u)) >> 16);
}

// ws layout: qw 0..4MB, kw 4..8MB, vw 8..12MB, frag 12MB..+24KB, knnIdx +32KB..+1MB
#define OFF_QW   0u
#define OFF_KW   (4u << 20)
#define OFF_VW   (8u << 20)
#define OFF_FRAG (12u << 20)
#define OFF_KNN  ((12u << 20) + 32768u)     // ws >= 14.8 MB (established R12)

// ---------------------------------------------------------------------------
// prefrag: pack Wp2/Wt1/Wt2 into MFMA B-frag order (proven R11-R15).
// ---------------------------------------------------------------------------
__global__ void prefrag_kernel(const float* __restrict__ Wp2,
                               const float* __restrict__ Wt1,
                               const float* __restrict__ Wt2,
                               unsigned short* __restrict__ dst)
{
    int i = blockIdx.x * 256 + threadIdx.x;
    if (i >= 3 * 4096) return;
    int st = i >> 12, e = i & 4095;
    const float* W = (st == 0) ? Wp2 : (st == 1) ? Wt1 : Wt2;
    int k = e >> 6, n = e & 63;
    int s = k >> 5, quad = (k >> 3) & 3, j = k & 7;
    int t = n >> 4, l = quad * 16 + (n & 15);
    dst[st * 4096 + (s * 4 + t) * 512 + l * 8 + j] = f2b(W[e]);
}

// ---------------------------------------------------------------------------
// proj v2: LDS-staged weights (proven R14+). Inner math f32, bit-identical.
// ---------------------------------------------------------------------------
__global__ __launch_bounds__(1024) void proj_kernel(
    const float* __restrict__ feat,
    const float* __restrict__ Wk, const float* __restrict__ bk,
    const float* __restrict__ Wq, const float* __restrict__ Wks,
    const float* __restrict__ Wv,
    float* __restrict__ qw, float* __restrict__ kw, float* __restrict__ vw)
{
    __shared__ __align__(16) float4 sW[4][1024];   // Wk, Wq, Wks, Wv (64 KB)
    int tid = threadIdx.x;
    sW[0][tid] = ((const float4*)Wk)[tid];
    sW[1][tid] = ((const float4*)Wq)[tid];
    sW[2][tid] = ((const float4*)Wks)[tid];
    sW[3][tid] = ((const float4*)Wv)[tid];
    __syncthreads();
    const float* sWk  = (const float*)sW[0];
    const float* sWq  = (const float*)sW[1];
    const float* sWks = (const float*)sW[2];
    const float* sWv  = (const float*)sW[3];

    int w = tid >> 6, lane = tid & 63;
    int p = blockIdx.x * 16 + w;
    float f = feat[(size_t)p * HDIM + lane];
    float x = bk[lane];
    #pragma unroll 8
    for (int c = 0; c < 64; ++c) x += __shfl(f, c) * sWk[c * 64 + lane];
    float q = 0.f, k = 0.f, v = 0.f;
    #pragma unroll 8
    for (int c = 0; c < 64; ++c) {
        float xc = __shfl(x, c);
        q += xc * sWq[c * 64 + lane];
        k += xc * sWks[c * 64 + lane];
        v += xc * sWv[c * 64 + lane];
    }
    qw[(size_t)p * HDIM + lane] = q;
    kw[(size_t)p * HDIM + lane] = k;
    vw[(size_t)p * HDIM + lane] = v;
}

// ---------------------------------------------------------------------------
// knn v7: half-scan wave split (R19 structure) with the scratch-spill bug
// fixed. R19 post-mortem: `#pragma unroll 1` on the per-qi extraction loop
// made dh[qi]/ih[qi] runtime-indexed -> compiler demoted the whole top-4
// state + repair heap to LOCAL MEMORY (VGPR 60->32, WRITE_SIZE 1MB->9.9GB,
// 7.6ms of scratch traffic). Rule #20. Fix: fully unroll every loop that
// indexes per-thread arrays (qi extraction, merge), exactly like R18's
// proven codegen. Half-split machinery unchanged (verified correct in R19:
// passed absmax).
// ---------------------------------------------------------------------------
__global__ __launch_bounds__(256, 8) void knnh_kernel(
    const float* __restrict__ xyzp, int* __restrict__ knnIdx)
{
    __shared__ float sD[2][2][4][16];   // [quad-in-block][half][qi][r]
    __shared__ int   sI[2][2][4][16];

    int w = threadIdx.x >> 6, lane = threadIdx.x & 63;
    int qsel = w >> 1, half = w & 1;
    int wid = blockIdx.x * 2 + qsel;     // quad id 0..4095
    int pbase = wid * 4;                 // 4 consecutive points, same batch
    int b = pbase >> 13;
    int nbase = pbase & (NPTS - 1);
    const float4* xb4 = (const float4*)xyzp + (size_t)b * NPTS;
    int cbase = half * (NPTS / 2);       // this wave's candidate half

    float qx[4], qy[4], qz[4], qs[4];
    #pragma unroll
    for (int qi = 0; qi < 4; ++qi) {
        float4 s = xb4[nbase + qi];
        qx[qi] = s.x; qy[qi] = s.y; qz[qi] = s.z;
        qs[qi] = s.x * s.x + s.y * s.y + s.z * s.z;
    }

    float dh[4][4]; int ih[4][4];
    #pragma unroll
    for (int qi = 0; qi < 4; ++qi)
        #pragma unroll
        for (int j = 0; j < 4; ++j) { dh[qi][j] = 3.4e38f; ih[qi][j] = 0x7fffffff; }

    float tau[4];
    #pragma unroll
    for (int qi = 0; qi < 4; ++qi) tau[qi] = 3.4e38f;

    #pragma unroll 1
    for (int t = 0; t < NPTS / 512; ++t) {          // 16 iters x 256 cands
        float4 c[4];
        #pragma unroll
        for (int u = 0; u < 4; ++u)
            c[u] = xb4[cbase + (t * 4 + u) * 64 + lane];
        #pragma unroll
        for (int u = 0; u < 4; ++u) {
            int m = cbase + (t * 4 + u) * 64 + lane;
            float cs = c[u].x * c[u].x + c[u].y * c[u].y + c[u].z * c[u].z;
            #pragma unroll
            for (int qi = 0; qi < 4; ++qi) {
                float d = qs[qi] + cs
                        - 2.0f * (qx[qi] * c[u].x + qy[qi] * c[u].y + qz[qi] * c[u].z);
                if (__any(d <= tau[qi])) {
                    bool c3 = d < dh[qi][3];
                    bool c2 = d < dh[qi][2];
                    bool c1 = d < dh[qi][1];
                    bool c0 = d < dh[qi][0];
                    dh[qi][3] = c2 ? dh[qi][2] : (c3 ? d : dh[qi][3]);
                    ih[qi][3] = c2 ? ih[qi][2] : (c3 ? m : ih[qi][3]);
                    dh[qi][2] = c1 ? dh[qi][1] : (c2 ? d : dh[qi][2]);
                    ih[qi][2] = c1 ? ih[qi][1] : (c2 ? m : ih[qi][2]);
                    dh[qi][1] = c0 ? dh[qi][0] : (c1 ? d : dh[qi][1]);
                    ih[qi][1] = c0 ? ih[qi][0] : (c1 ? m : ih[qi][1]);
                    dh[qi][0] = c0 ? d : dh[qi][0];
                    ih[qi][0] = c0 ? m : ih[qi][0];
                }
            }
        }
        if (t & 1) {
            // tau = max over 4 groups-of-16 of (min over group of dh[3]):
            // upper bound on this half's 16th-best (proven R18)
            #pragma unroll
            for (int qi = 0; qi < 4; ++qi) {
                float t4 = dh[qi][3];
                t4 = fminf(t4, __shfl_xor(t4, 1));
                t4 = fminf(t4, __shfl_xor(t4, 2));
                t4 = fminf(t4, __shfl_xor(t4, 4));
                t4 = fminf(t4, __shfl_xor(t4, 8));
                t4 = fmaxf(t4, __shfl_xor(t4, 16));
                t4 = fmaxf(t4, __shfl_xor(t4, 32));
                tau[qi] = t4;
            }
        }
    }

    // per-qi: exact half-top-16 extraction (+ repair over own half), to LDS.
    // MUST be fully unrolled: dh/ih/eh/ei indexed by qi (rule #20 / R19 bug).
    #pragma unroll
    for (int qi = 0; qi < 4; ++qi) {
        float mynd = 3.4e38f; int mynb = 0x7fffffff; int head = 0;
        #pragma unroll 1
        for (int r = 0; r < KNN; ++r) {
            float d = dh[qi][0]; int i = ih[qi][0];
            #pragma unroll
            for (int s = 1; s < 64; s <<= 1) {
                float d2 = __shfl_xor(d, s); int i2 = __shfl_xor(i, s);
                if (d2 < d || (d2 == d && i2 < i)) { d = d2; i = i2; }
            }
            if (lane == r) { mynb = i; mynd = d; }
            if (ih[qi][0] == i) {
                dh[qi][0] = dh[qi][1]; ih[qi][0] = ih[qi][1];
                dh[qi][1] = dh[qi][2]; ih[qi][1] = ih[qi][2];
                dh[qi][2] = dh[qi][3]; ih[qi][2] = ih[qi][3];
                dh[qi][3] = 3.4e38f; ih[qi][3] = 0x7fffffff;
                ++head;
            }
        }
        // exact repair over own half (proven pattern, range-restricted)
        if (__any(head >= 4)) {
            float eh[16]; int ei[16];
            #pragma unroll
            for (int j = 0; j < 16; ++j) { eh[j] = 3.4e38f; ei[j] = 0x7fffffff; }
            for (int t = 0; t < (NPTS / 2) / 64; ++t) {
                int m = cbase + t * 64 + lane;
                float4 c4 = xb4[m];
                float cs = c4.x * c4.x + c4.y * c4.y + c4.z * c4.z;
                float d = qs[qi] + cs
                        - 2.0f * (qx[qi] * c4.x + qy[qi] * c4.y + qz[qi] * c4.z);
                if (d < eh[15]) {
                    eh[15] = d; ei[15] = m;
                    #pragma unroll
                    for (int j = 15; j >= 1; --j)
                        if (eh[j] < eh[j - 1]) {
                            float td = eh[j]; eh[j] = eh[j - 1]; eh[j - 1] = td;
                            int ti = ei[j]; ei[j] = ei[j - 1]; ei[j - 1] = ti;
                        }
                }
            }
            #pragma unroll 1
            for (int r = 0; r < KNN; ++r) {
                float d = eh[0]; int i = ei[0];
                #pragma unroll
                for (int s = 1; s < 64; s <<= 1) {
                    float d2 = __shfl_xor(d, s); int i2 = __shfl_xor(i, s);
                    if (d2 < d || (d2 == d && i2 < i)) { d = d2; i = i2; }
                }
                if (lane == r) { mynb = i; mynd = d; }
                if (ei[0] == i) {
                    #pragma unroll
                    for (int j = 0; j < 15; ++j) { eh[j] = eh[j + 1]; ei[j] = ei[j + 1]; }
                    eh[15] = 3.4e38f; ei[15] = 0x7fffffff;
                }
            }
        }
        if (lane < KNN) {
            sD[qsel][half][qi][lane] = mynd;
            sI[qsel][half][qi][lane] = mynb;
        }
    }
    __syncthreads();

    // merge 16+16 -> 16 per qi (indices disjoint across halves -> knockout
    // by index is unambiguous); half-0 wave writes. Fully unrolled.
    #pragma unroll
    for (int qi = 0; qi < 4; ++qi) {
        float d = 3.4e38f; int idx = 0x7fffffff;
        if (lane < 32) {
            d   = sD[qsel][lane >> 4][qi][lane & 15];
            idx = sI[qsel][lane >> 4][qi][lane & 15];
        }
        int outv = 0;
        #pragma unroll 1
        for (int r = 0; r < KNN; ++r) {
            float dm = d; int im = idx;
            #pragma unroll
            for (int s = 1; s < 64; s <<= 1) {
                float d2 = __shfl_xor(dm, s); int i2 = __shfl_xor(im, s);
                if (d2 < dm || (d2 == dm && i2 < im)) { dm = d2; im = i2; }
            }
            if (lane == r) outv = im;
            if (idx == im) d = 3.4e38f;
        }
        outv = min(max(outv, 0), NPTS - 1);
        if (half == 0 && lane < KNN)
            knnIdx[(size_t)(pbase + qi) * KNN + lane] = outv;
    }
}

// ---------------------------------------------------------------------------
// main: MFMA per-neighbor MLPs consuming knnIdx (proven verbatim R12/R14/R15).
// ---------------------------------------------------------------------------
__global__ __launch_bounds__(256) void LocalTransformer_80513456931527_kernel(
    const float* __restrict__ xyzp, const float* __restrict__ features,
    const float* __restrict__ Wp1,  const float* __restrict__ bp1,
    const float* __restrict__ bp2,  const float* __restrict__ bt1,
    const float* __restrict__ bt2,
    const float* __restrict__ Wa,   const float* __restrict__ ba,
    const float* __restrict__ qw, const float* __restrict__ kw,
    const float* __restrict__ vw,
    const unsigned short* __restrict__ fragw,
    const int* __restrict__ knnIdx,
    float* __restrict__ out)
{
    __shared__ __align__(16) float sBounce[4][16 * 68 + 4];

    int tid = threadIdx.x, w = tid >> 6, lane = tid & 63;
    int p = blockIdx.x * 4 + w;
    int b = p >> 13;
    float* bb = sBounce[w];

    int quad = lane >> 4, l15 = lane & 15;
    int mynb = knnIdx[(size_t)p * KNN + l15];
    mynb = min(max(mynb, 0), NPTS - 1);
    int nb_a = mynb;
    int nbm[4];
    #pragma unroll
    for (int r = 0; r < 4; ++r) nbm[r] = __shfl(mynb, quad * 4 + r);

    const float4 xq4 = *(const float4*)(xyzp + (size_t)p * 4);
    const float4 xn4 = *(const float4*)(xyzp + ((size_t)b * NPTS + nb_a) * 4);
    float rel0 = xq4.x - xn4.x, rel1 = xq4.y - xn4.y;
    float rel2 = xq4.z - xn4.z, rel3 = xq4.w - xn4.w;

    bf8_t pe1f[2];
    #pragma unroll
    for (int s = 0; s < 2; ++s) {
        int hb = s * 32 + quad * 8;
        float W0[8], W1[8], W2[8], W3[8], Bb[8];
        *(float4*)&W0[0] = *(const float4*)(Wp1 +       hb);
        *(float4*)&W0[4] = *(const float4*)(Wp1 +       hb + 4);
        *(float4*)&W1[0] = *(const float4*)(Wp1 +  64 + hb);
        *(float4*)&W1[4] = *(const float4*)(Wp1 +  64 + hb + 4);
        *(float4*)&W2[0] = *(const float4*)(Wp1 + 128 + hb);
        *(float4*)&W2[4] = *(const float4*)(Wp1 + 128 + hb + 4);
        *(float4*)&W3[0] = *(const float4*)(Wp1 + 192 + hb);
        *(float4*)&W3[4] = *(const float4*)(Wp1 + 192 + hb + 4);
        *(float4*)&Bb[0] = *(const float4*)(bp1 + hb);
        *(float4*)&Bb[4] = *(const float4*)(bp1 + hb + 4);
        #pragma unroll
        for (int j = 0; j < 8; ++j) {
            float a = Bb[j] + rel0 * W0[j] + rel1 * W1[j]
                            + rel2 * W2[j] + rel3 * W3[j];
            pe1f[s][j] = (short)f2b(fmaxf(a, 0.f));
        }
    }

    const bf8_t* BW = (const bf8_t*)fragw;
    f4_t pe2c[4];
    #pragma unroll
    for (int t = 0; t < 4; ++t) {
        f4_t acc = {0.f, 0.f, 0.f, 0.f};
        acc = MFMA16(pe1f[0], BW[0 * 512 + (0 * 4 + t) * 64 + lane], acc);
        acc = MFMA16(pe1f[1], BW[0 * 512 + (1 * 4 + t) * 64 + lane], acc);
        float bias = bp2[t * 16 + l15];
        #pragma unroll
        for (int r = 0; r < 4; ++r) acc[r] += bias;
        pe2c[t] = acc;
    }

    f4_t ainc[4], vpec[4];
    #pragma unroll
    for (int t = 0; t < 4; ++t) {
        float qv = qw[(size_t)p * HDIM + t * 16 + l15];
        #pragma unroll
        for (int r = 0; r < 4; ++r) {
            size_t nbo = ((size_t)b * NPTS + nbm[r]) * HDIM + t * 16 + l15;
            ainc[t][r] = qv - kw[nbo] + pe2c[t][r];
            vpec[t][r] = vw[nbo] + pe2c[t][r];
        }
    }

    #pragma unroll
    for (int t = 0; t < 4; ++t)
        #pragma unroll
        for (int r = 0; r < 4; ++r)
            bb[(quad * 4 + r) * 68 + t * 16 + l15] = ainc[t][r];
    asm volatile("s_waitcnt lgkmcnt(0)" ::: "memory");
    bf8_t af[2];
    #pragma unroll
    for (int s = 0; s < 2; ++s) {
        float tmp[8];
        *(float4*)&tmp[0] = *(const float4*)&bb[l15 * 68 + s * 32 + quad * 8];
        *(float4*)&tmp[4] = *(const float4*)&bb[l15 * 68 + s * 32 + quad * 8 + 4];
        #pragma unroll
        for (int j = 0; j < 8; ++j) af[s][j] = (short)f2b(tmp[j]);
    }

    f4_t t1c[4];
    #pragma unroll
    for (int t = 0; t < 4; ++t) {
        f4_t acc = {0.f, 0.f, 0.f, 0.f};
        acc = MFMA16(af[0], BW[1 * 512 + (0 * 4 + t) * 64 + lane], acc);
        acc = MFMA16(af[1], BW[1 * 512 + (1 * 4 + t) * 64 + lane], acc);
        float bias = bt1[t * 16 + l15];
        #pragma unroll
        for (int r = 0; r < 4; ++r) t1c[t][r] = fmaxf(acc[r] + bias, 0.f);
    }

    asm volatile("s_waitcnt lgkmcnt(0)" ::: "memory");
    #pragma unroll
    for (int t = 0; t < 4; ++t)
        #pragma unroll
        for (int r = 0; r < 4; ++r)
            bb[(quad * 4 + r) * 68 + t * 16 + l15] = t1c[t][r];
    asm volatile("s_waitcnt lgkmcnt(0)" ::: "memory");
    bf8_t tf[2];
    #pragma unroll
    for (int s = 0; s < 2; ++s) {
        float tmp[8];
        *(float4*)&tmp[0] = *(const float4*)&bb[l15 * 68 + s * 32 + quad * 8];
        *(float4*)&tmp[4] = *(const float4*)&bb[l15 * 68 + s * 32 + quad * 8 + 4];
        #pragma unroll
        for (int j = 0; j < 8; ++j) tf[s][j] = (short)f2b(tmp[j]);
    }

    f4_t lgc[4];
    #pragma unroll
    for (int t = 0; t < 4; ++t) {
        f4_t acc = {0.f, 0.f, 0.f, 0.f};
        acc = MFMA16(tf[0], BW[2 * 512 + (0 * 4 + t) * 64 + lane], acc);
        acc = MFMA16(tf[1], BW[2 * 512 + (1 * 4 + t) * 64 + lane], acc);
        float bias = bt2[t * 16 + l15];
        #pragma unroll
        for (int r = 0; r < 4; ++r) lgc[t][r] = (acc[r] + bias) * 0.125f;
    }

    float res[4];
    #pragma unroll
    for (int t = 0; t < 4; ++t) {
        float m0 = fmaxf(fmaxf(lgc[t][0], lgc[t][1]), fmaxf(lgc[t][2], lgc[t][3]));
        m0 = fmaxf(m0, __shfl_xor(m0, 16));
        m0 = fmaxf(m0, __shfl_xor(m0, 32));
        float e0 = fast_exp(lgc[t][0] - m0), e1 = fast_exp(lgc[t][1] - m0);
        float e2 = fast_exp(lgc[t][2] - m0), e3 = fast_exp(lgc[t][3] - m0);
        float sl = e0 + e1 + e2 + e3;
        float rl = e0 * vpec[t][0] + e1 * vpec[t][1]
                 + e2 * vpec[t][2] + e3 * vpec[t][3];
        sl += __shfl_xor(sl, 16); sl += __shfl_xor(sl, 32);
        rl += __shfl_xor(rl, 16); rl += __shfl_xor(rl, 32);
        res[t] = rl / sl;
    }

    float rh = (quad == 0) ? res[0] : (quad == 1) ? res[1]
             : (quad == 2) ? res[2] : res[3];
    float f = features[(size_t)p * HDIM + lane];
    float o = ba[lane];
    #pragma unroll 8
    for (int c = 0; c < 64; ++c) o += __shfl(rh, c) * Wa[c * 64 + lane];
    out[(size_t)p * HDIM + lane] = o + f;
}

// ---------------------------------------------------------------------------
extern "C" void kernel_launch(void* const* d_in, const int* in_sizes, int n_in,
                              void* d_out, int out_size, void* d_ws, size_t ws_size,
                              hipStream_t stream)
{
    (void)in_sizes; (void)n_in; (void)out_size; (void)ws_size;
    const float* xyzp     = (const float*)d_in[0];
    const float* features = (const float*)d_in[1];
    const float* Wk  = (const float*)d_in[2];
    const float* bk  = (const float*)d_in[3];
    const float* Wq  = (const float*)d_in[4];
    const float* Wks = (const float*)d_in[5];
    const float* Wv  = (const float*)d_in[6];
    const float* Wp1 = (const float*)d_in[7];
    const float* bp1 = (const float*)d_in[8];
    const float* Wp2 = (const float*)d_in[9];
    const float* bp2 = (const float*)d_in[10];
    const float* Wt1 = (const float*)d_in[11];
    const float* bt1 = (const float*)d_in[12];
    const float* Wt2 = (const float*)d_in[13];
    const float* bt2 = (const float*)d_in[14];
    const float* Wa  = (const float*)d_in[15];
    const float* ba  = (const float*)d_in[16];
    float* out = (float*)d_out;
    char* ws = (char*)d_ws;

    float* qw = (float*)(ws + OFF_QW);
    float* kw = (float*)(ws + OFF_KW);
    float* vw = (float*)(ws + OFF_VW);
    unsigned short* fragw = (unsigned short*)(ws + OFF_FRAG);
    int* knnIdx = (int*)(ws + OFF_KNN);

    prefrag_kernel<<<48, 256, 0, stream>>>(Wp2, Wt1, Wt2, fragw);
    proj_kernel<<<(2 * NPTS) / 16, 1024, 0, stream>>>(
        features, Wk, bk, Wq, Wks, Wv, qw, kw, vw);
    knnh_kernel<<<(2 * NPTS) / 8, 256, 0, stream>>>(xyzp, knnIdx);
    LocalTransformer_80513456931527_kernel<<<(2 * NPTS) / 4, 256, 0, stream>>>(
        xyzp, features, Wp1, bp1, bp2, bt1, bt2, Wa, ba,
        qw, kw, vw, fragw, knnIdx, out);
}

// Round 6
// 481.415 us; speedup vs baseline: 15.9480x; 1.6916x over previous
//
#include <hip/hip_runtime.h>

#define NPTS 8192
#define HDIM 64
#define KNN 16
#define LOG2E 1.4426950408889634f

typedef __attribute__((ext_vector_type(8))) short bf8_t;   // 8 bf16
typedef __attribute__((ext_vector_type(4))) float f4_t;    // MFMA C/D
#define MFMA16(a, b, c) __builtin_amdgcn_mfma_f32_16x16x32_bf16(a, b, c, 0, 0, 0)

__device__ __forceinline__ float fast_exp(float x) {
    float y = x * LOG2E;
    float r;
    asm volatile("v_exp_f32 %0, %1\n\ts_nop 1" : "=v"(r) : "v"(y));
    return r;
}
__device__ __forceinline__ unsigned short f2b(float x) {   // f32 -> bf16 RNE
    unsigned v = __float_as_uint(x);
    return (unsigned short)((v + 0x7FFFu + ((v >> 16) & 1u)) >> 16);
}

// ws layout: qw 0..4MB, kw 4..8MB, vw 8..12MB, frag 12MB..+24KB, knnIdx +32KB..+1MB
#define OFF_QW   0u
#define OFF_KW   (4u << 20)
#define OFF_VW   (8u << 20)
#define OFF_FRAG (12u << 20)
#define OFF_KNN  ((12u << 20) + 32768u)     // ws >= 14.8 MB (established R12)

// ---------------------------------------------------------------------------
// prefrag: pack Wp2/Wt1/Wt2 into MFMA B-frag order (proven R11-R15).
// ---------------------------------------------------------------------------
__global__ void prefrag_kernel(const float* __restrict__ Wp2,
                               const float* __restrict__ Wt1,
                               const float* __restrict__ Wt2,
                               unsigned short* __restrict__ dst)
{
    int i = blockIdx.x * 256 + threadIdx.x;
    if (i >= 3 * 4096) return;
    int st = i >> 12, e = i & 4095;
    const float* W = (st == 0) ? Wp2 : (st == 1) ? Wt1 : Wt2;
    int k = e >> 6, n = e & 63;
    int s = k >> 5, quad = (k >> 3) & 3, j = k & 7;
    int t = n >> 4, l = quad * 16 + (n & 15);
    dst[st * 4096 + (s * 4 + t) * 512 + l * 8 + j] = f2b(W[e]);
}

// ---------------------------------------------------------------------------
// proj v2: LDS-staged weights (proven R14+). Inner math f32, bit-identical.
// ---------------------------------------------------------------------------
__global__ __launch_bounds__(1024) void proj_kernel(
    const float* __restrict__ feat,
    const float* __restrict__ Wk, const float* __restrict__ bk,
    const float* __restrict__ Wq, const float* __restrict__ Wks,
    const float* __restrict__ Wv,
    float* __restrict__ qw, float* __restrict__ kw, float* __restrict__ vw)
{
    __shared__ __align__(16) float4 sW[4][1024];   // Wk, Wq, Wks, Wv (64 KB)
    int tid = threadIdx.x;
    sW[0][tid] = ((const float4*)Wk)[tid];
    sW[1][tid] = ((const float4*)Wq)[tid];
    sW[2][tid] = ((const float4*)Wks)[tid];
    sW[3][tid] = ((const float4*)Wv)[tid];
    __syncthreads();
    const float* sWk  = (const float*)sW[0];
    const float* sWq  = (const float*)sW[1];
    const float* sWks = (const float*)sW[2];
    const float* sWv  = (const float*)sW[3];

    int w = tid >> 6, lane = tid & 63;
    int p = blockIdx.x * 16 + w;
    float f = feat[(size_t)p * HDIM + lane];
    float x = bk[lane];
    #pragma unroll 8
    for (int c = 0; c < 64; ++c) x += __shfl(f, c) * sWk[c * 64 + lane];
    float q = 0.f, k = 0.f, v = 0.f;
    #pragma unroll 8
    for (int c = 0; c < 64; ++c) {
        float xc = __shfl(x, c);
        q += xc * sWq[c * 64 + lane];
        k += xc * sWks[c * 64 + lane];
        v += xc * sWv[c * 64 + lane];
    }
    qw[(size_t)p * HDIM + lane] = q;
    kw[(size_t)p * HDIM + lane] = k;
    vw[(size_t)p * HDIM + lane] = v;
}

// ---------------------------------------------------------------------------
// knn v8: half-scan wave split, REGISTER-FEASIBLE launch bounds.
// R20 post-mortem: __launch_bounds__(256, 8) caps the allocator at 512/8=64
// VGPRs; live state (dh/ih 32 + q 16 + c[4] 16 + tau/addr ~ 90) doesn't fit
// -> compiler spilled the top-4 state to scratch to honor the bound
// (VGPR=32, WRITE_SIZE=1.56 GB, FETCH=194 MB of scratch round-trips, 665us).
// Fix: plain __launch_bounds__(256) — let the allocator pick (~60 VGPR like
// R18's near-identical machinery). VGPR <= 64 still permits 8 waves/SIMD,
// and the 2048-block grid supplies them. Algorithm unchanged from R19/R20
// (verified: both passed absmax despite the spills).
// ---------------------------------------------------------------------------
__global__ __launch_bounds__(256) void knnh_kernel(
    const float* __restrict__ xyzp, int* __restrict__ knnIdx)
{
    __shared__ float sD[2][2][4][16];   // [quad-in-block][half][qi][r]
    __shared__ int   sI[2][2][4][16];

    int w = threadIdx.x >> 6, lane = threadIdx.x & 63;
    int qsel = w >> 1, half = w & 1;
    int wid = blockIdx.x * 2 + qsel;     // quad id 0..4095
    int pbase = wid * 4;                 // 4 consecutive points, same batch
    int b = pbase >> 13;
    int nbase = pbase & (NPTS - 1);
    const float4* xb4 = (const float4*)xyzp + (size_t)b * NPTS;
    int cbase = half * (NPTS / 2);       // this wave's candidate half

    float qx[4], qy[4], qz[4], qs[4];
    #pragma unroll
    for (int qi = 0; qi < 4; ++qi) {
        float4 s = xb4[nbase + qi];
        qx[qi] = s.x; qy[qi] = s.y; qz[qi] = s.z;
        qs[qi] = s.x * s.x + s.y * s.y + s.z * s.z;
    }

    float dh[4][4]; int ih[4][4];
    #pragma unroll
    for (int qi = 0; qi < 4; ++qi)
        #pragma unroll
        for (int j = 0; j < 4; ++j) { dh[qi][j] = 3.4e38f; ih[qi][j] = 0x7fffffff; }

    float tau[4];
    #pragma unroll
    for (int qi = 0; qi < 4; ++qi) tau[qi] = 3.4e38f;

    #pragma unroll 1
    for (int t = 0; t < NPTS / 512; ++t) {          // 16 iters x 256 cands
        float4 c[4];
        #pragma unroll
        for (int u = 0; u < 4; ++u)
            c[u] = xb4[cbase + (t * 4 + u) * 64 + lane];
        #pragma unroll
        for (int u = 0; u < 4; ++u) {
            int m = cbase + (t * 4 + u) * 64 + lane;
            float cs = c[u].x * c[u].x + c[u].y * c[u].y + c[u].z * c[u].z;
            #pragma unroll
            for (int qi = 0; qi < 4; ++qi) {
                float d = qs[qi] + cs
                        - 2.0f * (qx[qi] * c[u].x + qy[qi] * c[u].y + qz[qi] * c[u].z);
                if (__any(d <= tau[qi])) {
                    bool c3 = d < dh[qi][3];
                    bool c2 = d < dh[qi][2];
                    bool c1 = d < dh[qi][1];
                    bool c0 = d < dh[qi][0];
                    dh[qi][3] = c2 ? dh[qi][2] : (c3 ? d : dh[qi][3]);
                    ih[qi][3] = c2 ? ih[qi][2] : (c3 ? m : ih[qi][3]);
                    dh[qi][2] = c1 ? dh[qi][1] : (c2 ? d : dh[qi][2]);
                    ih[qi][2] = c1 ? ih[qi][1] : (c2 ? m : ih[qi][2]);
                    dh[qi][1] = c0 ? dh[qi][0] : (c1 ? d : dh[qi][1]);
                    ih[qi][1] = c0 ? ih[qi][0] : (c1 ? m : ih[qi][1]);
                    dh[qi][0] = c0 ? d : dh[qi][0];
                    ih[qi][0] = c0 ? m : ih[qi][0];
                }
            }
        }
        if (t & 1) {
            // tau = max over 4 groups-of-16 of (min over group of dh[3]):
            // upper bound on this half's 16th-best (proven R18)
            #pragma unroll
            for (int qi = 0; qi < 4; ++qi) {
                float t4 = dh[qi][3];
                t4 = fminf(t4, __shfl_xor(t4, 1));
                t4 = fminf(t4, __shfl_xor(t4, 2));
                t4 = fminf(t4, __shfl_xor(t4, 4));
                t4 = fminf(t4, __shfl_xor(t4, 8));
                t4 = fmaxf(t4, __shfl_xor(t4, 16));
                t4 = fmaxf(t4, __shfl_xor(t4, 32));
                tau[qi] = t4;
            }
        }
    }

    // per-qi: exact half-top-16 extraction (+ repair over own half), to LDS.
    // MUST be fully unrolled: dh/ih/eh/ei indexed by qi (rule #20 / R19 bug).
    #pragma unroll
    for (int qi = 0; qi < 4; ++qi) {
        float mynd = 3.4e38f; int mynb = 0x7fffffff; int head = 0;
        #pragma unroll 1
        for (int r = 0; r < KNN; ++r) {
            float d = dh[qi][0]; int i = ih[qi][0];
            #pragma unroll
            for (int s = 1; s < 64; s <<= 1) {
                float d2 = __shfl_xor(d, s); int i2 = __shfl_xor(i, s);
                if (d2 < d || (d2 == d && i2 < i)) { d = d2; i = i2; }
            }
            if (lane == r) { mynb = i; mynd = d; }
            if (ih[qi][0] == i) {
                dh[qi][0] = dh[qi][1]; ih[qi][0] = ih[qi][1];
                dh[qi][1] = dh[qi][2]; ih[qi][1] = ih[qi][2];
                dh[qi][2] = dh[qi][3]; ih[qi][2] = ih[qi][3];
                dh[qi][3] = 3.4e38f; ih[qi][3] = 0x7fffffff;
                ++head;
            }
        }
        // exact repair over own half (proven pattern, range-restricted)
        if (__any(head >= 4)) {
            float eh[16]; int ei[16];
            #pragma unroll
            for (int j = 0; j < 16; ++j) { eh[j] = 3.4e38f; ei[j] = 0x7fffffff; }
            for (int t = 0; t < (NPTS / 2) / 64; ++t) {
                int m = cbase + t * 64 + lane;
                float4 c4 = xb4[m];
                float cs = c4.x * c4.x + c4.y * c4.y + c4.z * c4.z;
                float d = qs[qi] + cs
                        - 2.0f * (qx[qi] * c4.x + qy[qi] * c4.y + qz[qi] * c4.z);
                if (d < eh[15]) {
                    eh[15] = d; ei[15] = m;
                    #pragma unroll
                    for (int j = 15; j >= 1; --j)
                        if (eh[j] < eh[j - 1]) {
                            float td = eh[j]; eh[j] = eh[j - 1]; eh[j - 1] = td;
                            int ti = ei[j]; ei[j] = ei[j - 1]; ei[j - 1] = ti;
                        }
                }
            }
            #pragma unroll 1
            for (int r = 0; r < KNN; ++r) {
                float d = eh[0]; int i = ei[0];
                #pragma unroll
                for (int s = 1; s < 64; s <<= 1) {
                    float d2 = __shfl_xor(d, s); int i2 = __shfl_xor(i, s);
                    if (d2 < d || (d2 == d && i2 < i)) { d = d2; i = i2; }
                }
                if (lane == r) { mynb = i; mynd = d; }
                if (ei[0] == i) {
                    #pragma unroll
                    for (int j = 0; j < 15; ++j) { eh[j] = eh[j + 1]; ei[j] = ei[j + 1]; }
                    eh[15] = 3.4e38f; ei[15] = 0x7fffffff;
                }
            }
        }
        if (lane < KNN) {
            sD[qsel][half][qi][lane] = mynd;
            sI[qsel][half][qi][lane] = mynb;
        }
    }
    __syncthreads();

    // merge 16+16 -> 16 per qi (indices disjoint across halves -> knockout
    // by index is unambiguous); half-0 wave writes. Fully unrolled.
    #pragma unroll
    for (int qi = 0; qi < 4; ++qi) {
        float d = 3.4e38f; int idx = 0x7fffffff;
        if (lane < 32) {
            d   = sD[qsel][lane >> 4][qi][lane & 15];
            idx = sI[qsel][lane >> 4][qi][lane & 15];
        }
        int outv = 0;
        #pragma unroll 1
        for (int r = 0; r < KNN; ++r) {
            float dm = d; int im = idx;
            #pragma unroll
            for (int s = 1; s < 64; s <<= 1) {
                float d2 = __shfl_xor(dm, s); int i2 = __shfl_xor(im, s);
                if (d2 < dm || (d2 == dm && i2 < im)) { dm = d2; im = i2; }
            }
            if (lane == r) outv = im;
            if (idx == im) d = 3.4e38f;
        }
        outv = min(max(outv, 0), NPTS - 1);
        if (half == 0 && lane < KNN)
            knnIdx[(size_t)(pbase + qi) * KNN + lane] = outv;
    }
}

// ---------------------------------------------------------------------------
// main: MFMA per-neighbor MLPs consuming knnIdx (proven verbatim R12/R14/R15).
// ---------------------------------------------------------------------------
__global__ __launch_bounds__(256) void LocalTransformer_80513456931527_kernel(
    const float* __restrict__ xyzp, const float* __restrict__ features,
    const float* __restrict__ Wp1,  const float* __restrict__ bp1,
    const float* __restrict__ bp2,  const float* __restrict__ bt1,
    const float* __restrict__ bt2,
    const float* __restrict__ Wa,   const float* __restrict__ ba,
    const float* __restrict__ qw, const float* __restrict__ kw,
    const float* __restrict__ vw,
    const unsigned short* __restrict__ fragw,
    const int* __restrict__ knnIdx,
    float* __restrict__ out)
{
    __shared__ __align__(16) float sBounce[4][16 * 68 + 4];

    int tid = threadIdx.x, w = tid >> 6, lane = tid & 63;
    int p = blockIdx.x * 4 + w;
    int b = p >> 13;
    float* bb = sBounce[w];

    int quad = lane >> 4, l15 = lane & 15;
    int mynb = knnIdx[(size_t)p * KNN + l15];
    mynb = min(max(mynb, 0), NPTS - 1);
    int nb_a = mynb;
    int nbm[4];
    #pragma unroll
    for (int r = 0; r < 4; ++r) nbm[r] = __shfl(mynb, quad * 4 + r);

    const float4 xq4 = *(const float4*)(xyzp + (size_t)p * 4);
    const float4 xn4 = *(const float4*)(xyzp + ((size_t)b * NPTS + nb_a) * 4);
    float rel0 = xq4.x - xn4.x, rel1 = xq4.y - xn4.y;
    float rel2 = xq4.z - xn4.z, rel3 = xq4.w - xn4.w;

    bf8_t pe1f[2];
    #pragma unroll
    for (int s = 0; s < 2; ++s) {
        int hb = s * 32 + quad * 8;
        float W0[8], W1[8], W2[8], W3[8], Bb[8];
        *(float4*)&W0[0] = *(const float4*)(Wp1 +       hb);
        *(float4*)&W0[4] = *(const float4*)(Wp1 +       hb + 4);
        *(float4*)&W1[0] = *(const float4*)(Wp1 +  64 + hb);
        *(float4*)&W1[4] = *(const float4*)(Wp1 +  64 + hb + 4);
        *(float4*)&W2[0] = *(const float4*)(Wp1 + 128 + hb);
        *(float4*)&W2[4] = *(const float4*)(Wp1 + 128 + hb + 4);
        *(float4*)&W3[0] = *(const float4*)(Wp1 + 192 + hb);
        *(float4*)&W3[4] = *(const float4*)(Wp1 + 192 + hb + 4);
        *(float4*)&Bb[0] = *(const float4*)(bp1 + hb);
        *(float4*)&Bb[4] = *(const float4*)(bp1 + hb + 4);
        #pragma unroll
        for (int j = 0; j < 8; ++j) {
            float a = Bb[j] + rel0 * W0[j] + rel1 * W1[j]
                            + rel2 * W2[j] + rel3 * W3[j];
            pe1f[s][j] = (short)f2b(fmaxf(a, 0.f));
        }
    }

    const bf8_t* BW = (const bf8_t*)fragw;
    f4_t pe2c[4];
    #pragma unroll
    for (int t = 0; t < 4; ++t) {
        f4_t acc = {0.f, 0.f, 0.f, 0.f};
        acc = MFMA16(pe1f[0], BW[0 * 512 + (0 * 4 + t) * 64 + lane], acc);
        acc = MFMA16(pe1f[1], BW[0 * 512 + (1 * 4 + t) * 64 + lane], acc);
        float bias = bp2[t * 16 + l15];
        #pragma unroll
        for (int r = 0; r < 4; ++r) acc[r] += bias;
        pe2c[t] = acc;
    }

    f4_t ainc[4], vpec[4];
    #pragma unroll
    for (int t = 0; t < 4; ++t) {
        float qv = qw[(size_t)p * HDIM + t * 16 + l15];
        #pragma unroll
        for (int r = 0; r < 4; ++r) {
            size_t nbo = ((size_t)b * NPTS + nbm[r]) * HDIM + t * 16 + l15;
            ainc[t][r] = qv - kw[nbo] + pe2c[t][r];
            vpec[t][r] = vw[nbo] + pe2c[t][r];
        }
    }

    #pragma unroll
    for (int t = 0; t < 4; ++t)
        #pragma unroll
        for (int r = 0; r < 4; ++r)
            bb[(quad * 4 + r) * 68 + t * 16 + l15] = ainc[t][r];
    asm volatile("s_waitcnt lgkmcnt(0)" ::: "memory");
    bf8_t af[2];
    #pragma unroll
    for (int s = 0; s < 2; ++s) {
        float tmp[8];
        *(float4*)&tmp[0] = *(const float4*)&bb[l15 * 68 + s * 32 + quad * 8];
        *(float4*)&tmp[4] = *(const float4*)&bb[l15 * 68 + s * 32 + quad * 8 + 4];
        #pragma unroll
        for (int j = 0; j < 8; ++j) af[s][j] = (short)f2b(tmp[j]);
    }

    f4_t t1c[4];
    #pragma unroll
    for (int t = 0; t < 4; ++t) {
        f4_t acc = {0.f, 0.f, 0.f, 0.f};
        acc = MFMA16(af[0], BW[1 * 512 + (0 * 4 + t) * 64 + lane], acc);
        acc = MFMA16(af[1], BW[1 * 512 + (1 * 4 + t) * 64 + lane], acc);
        float bias = bt1[t * 16 + l15];
        #pragma unroll
        for (int r = 0; r < 4; ++r) t1c[t][r] = fmaxf(acc[r] + bias, 0.f);
    }

    asm volatile("s_waitcnt lgkmcnt(0)" ::: "memory");
    #pragma unroll
    for (int t = 0; t < 4; ++t)
        #pragma unroll
        for (int r = 0; r < 4; ++r)
            bb[(quad * 4 + r) * 68 + t * 16 + l15] = t1c[t][r];
    asm volatile("s_waitcnt lgkmcnt(0)" ::: "memory");
    bf8_t tf[2];
    #pragma unroll
    for (int s = 0; s < 2; ++s) {
        float tmp[8];
        *(float4*)&tmp[0] = *(const float4*)&bb[l15 * 68 + s * 32 + quad * 8];
        *(float4*)&tmp[4] = *(const float4*)&bb[l15 * 68 + s * 32 + quad * 8 + 4];
        #pragma unroll
        for (int j = 0; j < 8; ++j) tf[s][j] = (short)f2b(tmp[j]);
    }

    f4_t lgc[4];
    #pragma unroll
    for (int t = 0; t < 4; ++t) {
        f4_t acc = {0.f, 0.f, 0.f, 0.f};
        acc = MFMA16(tf[0], BW[2 * 512 + (0 * 4 + t) * 64 + lane], acc);
        acc = MFMA16(tf[1], BW[2 * 512 + (1 * 4 + t) * 64 + lane], acc);
        float bias = bt2[t * 16 + l15];
        #pragma unroll
        for (int r = 0; r < 4; ++r) lgc[t][r] = (acc[r] + bias) * 0.125f;
    }

    float res[4];
    #pragma unroll
    for (int t = 0; t < 4; ++t) {
        float m0 = fmaxf(fmaxf(lgc[t][0], lgc[t][1]), fmaxf(lgc[t][2], lgc[t][3]));
        m0 = fmaxf(m0, __shfl_xor(m0, 16));
        m0 = fmaxf(m0, __shfl_xor(m0, 32));
        float e0 = fast_exp(lgc[t][0] - m0), e1 = fast_exp(lgc[t][1] - m0);
        float e2 = fast_exp(lgc[t][2] - m0), e3 = fast_exp(lgc[t][3] - m0);
        float sl = e0 + e1 + e2 + e3;
        float rl = e0 * vpec[t][0] + e1 * vpec[t][1]
                 + e2 * vpec[t][2] + e3 * vpec[t][3];
        sl += __shfl_xor(sl, 16); sl += __shfl_xor(sl, 32);
        rl += __shfl_xor(rl, 16); rl += __shfl_xor(rl, 32);
        res[t] = rl / sl;
    }

    float rh = (quad == 0) ? res[0] : (quad == 1) ? res[1]
             : (quad == 2) ? res[2] : res[3];
    float f = features[(size_t)p * HDIM + lane];
    float o = ba[lane];
    #pragma unroll 8
    for (int c = 0; c < 64; ++c) o += __shfl(rh, c) * Wa[c * 64 + lane];
    out[(size_t)p * HDIM + lane] = o + f;
}

// ---------------------------------------------------------------------------
extern "C" void kernel_launch(void* const* d_in, const int* in_sizes, int n_in,
                              void* d_out, int out_size, void* d_ws, size_t ws_size,
                              hipStream_t stream)
{
    (void)in_sizes; (void)n_in; (void)out_size; (void)ws_size;
    const float* xyzp     = (const float*)d_in[0];
    const float* features = (const float*)d_in[1];
    const float* Wk  = (const float*)d_in[2];
    const float* bk  = (const float*)d_in[3];
    const float* Wq  = (const float*)d_in[4];
    const float* Wks = (const float*)d_in[5];
    const float* Wv  = (const float*)d_in[6];
    const float* Wp1 = (const float*)d_in[7];
    const float* bp1 = (const float*)d_in[8];
    const float* Wp2 = (const float*)d_in[9];
    const float* bp2 = (const float*)d_in[10];
    const float* Wt1 = (const float*)d_in[11];
    const float* bt1 = (const float*)d_in[12];
    const float* Wt2 = (const float*)d_in[13];
    const float* bt2 = (const float*)d_in[14];
    const float* Wa  = (const float*)d_in[15];
    const float* ba  = (const float*)d_in[16];
    float* out = (float*)d_out;
    char* ws = (char*)d_ws;

    float* qw = (float*)(ws + OFF_QW);
    float* kw = (float*)(ws + OFF_KW);
    float* vw = (float*)(ws + OFF_VW);
    unsigned short* fragw = (unsigned short*)(ws + OFF_FRAG);
    int* knnIdx = (int*)(ws + OFF_KNN);

    prefrag_kernel<<<48, 256, 0, stream>>>(Wp2, Wt1, Wt2, fragw);
    proj_kernel<<<(2 * NPTS) / 16, 1024, 0, stream>>>(
        features, Wk, bk, Wq, Wks, Wv, qw, kw, vw);
    knnh_kernel<<<(2 * NPTS) / 8, 256, 0, stream>>>(xyzp, knnIdx);
    LocalTransformer_80513456931527_kernel<<<(2 * NPTS) / 4, 256, 0, stream>>>(
        xyzp, features, Wp1, bp1, bp2, bt1, bt2, Wa, ba,
        qw, kw, vw, fragw, knnIdx, out);
}

// Round 8
// 354.515 us; speedup vs baseline: 21.6567x; 1.3580x over previous
//
#include <hip/hip_runtime.h>

#define NPTS 8192
#define HDIM 64
#define KNN 16
#define LOG2E 1.4426950408889634f

typedef __attribute__((ext_vector_type(8))) short bf8_t;   // 8 bf16
typedef __attribute__((ext_vector_type(4))) float f4_t;    // MFMA C/D
#define MFMA16(a, b, c) __builtin_amdgcn_mfma_f32_16x16x32_bf16(a, b, c, 0, 0, 0)

__device__ __forceinline__ float fast_exp(float x) {
    float y = x * LOG2E;
    float r;
    asm volatile("v_exp_f32 %0, %1\n\ts_nop 1" : "=v"(r) : "v"(y));
    return r;
}
__device__ __forceinline__ unsigned short f2b(float x) {   // f32 -> bf16 RNE
    unsigned v = __float_as_uint(x);
    return (unsigned short)((v + 0x7FFFu + ((v >> 16) & 1u)) >> 16);
}

// ws layout: qw 0..4MB, kw 4..8MB, vw 8..12MB, frag 12MB..+24KB, knnIdx +32KB..+1MB
#define OFF_QW   0u
#define OFF_KW   (4u << 20)
#define OFF_VW   (8u << 20)
#define OFF_FRAG (12u << 20)
#define OFF_KNN  ((12u << 20) + 32768u)     // ws >= 14.8 MB (established R12)

// ---------------------------------------------------------------------------
// prefrag: pack Wp2/Wt1/Wt2 into MFMA B-frag order (proven R11-R15).
// ---------------------------------------------------------------------------
__global__ void prefrag_kernel(const float* __restrict__ Wp2,
                               const float* __restrict__ Wt1,
                               const float* __restrict__ Wt2,
                               unsigned short* __restrict__ dst)
{
    int i = blockIdx.x * 256 + threadIdx.x;
    if (i >= 3 * 4096) return;
    int st = i >> 12, e = i & 4095;
    const float* W = (st == 0) ? Wp2 : (st == 1) ? Wt1 : Wt2;
    int k = e >> 6, n = e & 63;
    int s = k >> 5, quad = (k >> 3) & 3, j = k & 7;
    int t = n >> 4, l = quad * 16 + (n & 15);
    dst[st * 4096 + (s * 4 + t) * 512 + l * 8 + j] = f2b(W[e]);
}

// ---------------------------------------------------------------------------
// proj v2: LDS-staged weights (proven R14+). Inner math f32, bit-identical.
// ---------------------------------------------------------------------------
__global__ __launch_bounds__(1024) void proj_kernel(
    const float* __restrict__ feat,
    const float* __restrict__ Wk, const float* __restrict__ bk,
    const float* __restrict__ Wq, const float* __restrict__ Wks,
    const float* __restrict__ Wv,
    float* __restrict__ qw, float* __restrict__ kw, float* __restrict__ vw)
{
    __shared__ __align__(16) float4 sW[4][1024];   // Wk, Wq, Wks, Wv (64 KB)
    int tid = threadIdx.x;
    sW[0][tid] = ((const float4*)Wk)[tid];
    sW[1][tid] = ((const float4*)Wq)[tid];
    sW[2][tid] = ((const float4*)Wks)[tid];
    sW[3][tid] = ((const float4*)Wv)[tid];
    __syncthreads();
    const float* sWk  = (const float*)sW[0];
    const float* sWq  = (const float*)sW[1];
    const float* sWks = (const float*)sW[2];
    const float* sWv  = (const float*)sW[3];

    int w = tid >> 6, lane = tid & 63;
    int p = blockIdx.x * 16 + w;
    float f = feat[(size_t)p * HDIM + lane];
    float x = bk[lane];
    #pragma unroll 8
    for (int c = 0; c < 64; ++c) x += __shfl(f, c) * sWk[c * 64 + lane];
    float q = 0.f, k = 0.f, v = 0.f;
    #pragma unroll 8
    for (int c = 0; c < 64; ++c) {
        float xc = __shfl(x, c);
        q += xc * sWq[c * 64 + lane];
        k += xc * sWks[c * 64 + lane];
        v += xc * sWv[c * 64 + lane];
    }
    qw[(size_t)p * HDIM + lane] = q;
    kw[(size_t)p * HDIM + lane] = k;
    vw[(size_t)p * HDIM + lane] = v;
}

// ---------------------------------------------------------------------------
// knn v9 (resubmit — R7 bench was an infra failure, no data): FULL scan,
// 2 queries/wave (query-axis split, not candidate-axis).
// R21 post-mortem: half-scans issue 1.7x more VALU (busy-cy 288K->493K/SIMD)
// because tau-guard fire-mass ~ Sum_t min(1,4/t) is warmup-dominated and
// each half-scan pays the full warmup. Splitting the QUERY axis keeps total
// fire-mass fixed (16384 query-instances x full-scan warmup, same as R18)
// while doubling the grid: 8192 waves = 2048 blocks -> 8 waves/SIMD
// potential for latency hiding. Per-wave state drops to ~50 VGPR (dh/ih 16
// + q 8 + c[4] 16), register-feasible WITHOUT a constraining bound (R20
// lesson). Wave owns its 2 queries end-to-end: no LDS merge, no barrier;
// extraction + full-range repair = R18's proven code with qi<2.
// ---------------------------------------------------------------------------
__global__ __launch_bounds__(256) void knn2_kernel(
    const float* __restrict__ xyzp, int* __restrict__ knnIdx)
{
    int w = threadIdx.x >> 6, lane = threadIdx.x & 63;
    int wid = blockIdx.x * 4 + w;        // wave id 0..8191
    int pbase = wid * 2;                 // 2 consecutive points, same batch
    int b = pbase >> 13;
    int nbase = pbase & (NPTS - 1);
    const float4* xb4 = (const float4*)xyzp + (size_t)b * NPTS;

    float qx[2], qy[2], qz[2], qs[2];
    #pragma unroll
    for (int qi = 0; qi < 2; ++qi) {
        float4 s = xb4[nbase + qi];
        qx[qi] = s.x; qy[qi] = s.y; qz[qi] = s.z;
        qs[qi] = s.x * s.x + s.y * s.y + s.z * s.z;
    }

    float dh[2][4]; int ih[2][4];
    #pragma unroll
    for (int qi = 0; qi < 2; ++qi)
        #pragma unroll
        for (int j = 0; j < 4; ++j) { dh[qi][j] = 3.4e38f; ih[qi][j] = 0x7fffffff; }

    float tau[2];
    tau[0] = 3.4e38f; tau[1] = 3.4e38f;

    #pragma unroll 1
    for (int t = 0; t < NPTS / 256; ++t) {          // 32 iters x 256 cands
        float4 c[4];
        #pragma unroll
        for (int u = 0; u < 4; ++u)
            c[u] = xb4[(t * 4 + u) * 64 + lane];
        #pragma unroll
        for (int u = 0; u < 4; ++u) {
            int m = (t * 4 + u) * 64 + lane;
            float cs = c[u].x * c[u].x + c[u].y * c[u].y + c[u].z * c[u].z;
            #pragma unroll
            for (int qi = 0; qi < 2; ++qi) {
                float d = qs[qi] + cs
                        - 2.0f * (qx[qi] * c[u].x + qy[qi] * c[u].y + qz[qi] * c[u].z);
                if (__any(d <= tau[qi])) {
                    // branchless sorted insert (strict <, ties keep lower idx)
                    bool c3 = d < dh[qi][3];
                    bool c2 = d < dh[qi][2];
                    bool c1 = d < dh[qi][1];
                    bool c0 = d < dh[qi][0];
                    dh[qi][3] = c2 ? dh[qi][2] : (c3 ? d : dh[qi][3]);
                    ih[qi][3] = c2 ? ih[qi][2] : (c3 ? m : ih[qi][3]);
                    dh[qi][2] = c1 ? dh[qi][1] : (c2 ? d : dh[qi][2]);
                    ih[qi][2] = c1 ? ih[qi][1] : (c2 ? m : ih[qi][2]);
                    dh[qi][1] = c0 ? dh[qi][0] : (c1 ? d : dh[qi][1]);
                    ih[qi][1] = c0 ? ih[qi][0] : (c1 ? m : ih[qi][1]);
                    dh[qi][0] = c0 ? d : dh[qi][0];
                    ih[qi][0] = c0 ? m : ih[qi][0];
                }
            }
        }
        if (t & 1) {
            // tau = max over 4 groups-of-16 of (min over group of dh[3]):
            // valid upper bound on final global 16th-best (proven R18)
            #pragma unroll
            for (int qi = 0; qi < 2; ++qi) {
                float t4 = dh[qi][3];
                t4 = fminf(t4, __shfl_xor(t4, 1));
                t4 = fminf(t4, __shfl_xor(t4, 2));
                t4 = fminf(t4, __shfl_xor(t4, 4));
                t4 = fminf(t4, __shfl_xor(t4, 8));
                t4 = fmaxf(t4, __shfl_xor(t4, 16));
                t4 = fmaxf(t4, __shfl_xor(t4, 32));
                tau[qi] = t4;
            }
        }
    }

    // per-qi exact top-16 extraction + full-range repair (proven R18 code,
    // qi fully unrolled: rule #20).
    #pragma unroll
    for (int qi = 0; qi < 2; ++qi) {
        int mynb = 0, head = 0;
        #pragma unroll 1
        for (int r = 0; r < KNN; ++r) {
            float d = dh[qi][0]; int i = ih[qi][0];
            #pragma unroll
            for (int s = 1; s < 64; s <<= 1) {
                float d2 = __shfl_xor(d, s); int i2 = __shfl_xor(i, s);
                if (d2 < d || (d2 == d && i2 < i)) { d = d2; i = i2; }
            }
            if (lane == r) mynb = i;
            if (ih[qi][0] == i) {
                dh[qi][0] = dh[qi][1]; ih[qi][0] = ih[qi][1];
                dh[qi][1] = dh[qi][2]; ih[qi][1] = ih[qi][2];
                dh[qi][2] = dh[qi][3]; ih[qi][2] = ih[qi][3];
                dh[qi][3] = 3.4e38f; ih[qi][3] = 0x7fffffff;
                ++head;
            }
        }
        // exact repair (proven R13-R15): ~0.7%/query
        if (__any(head >= 4)) {
            float eh[16]; int ei[16];
            #pragma unroll
            for (int j = 0; j < 16; ++j) { eh[j] = 3.4e38f; ei[j] = 0x7fffffff; }
            for (int t = 0; t < NPTS / 64; ++t) {
                int m = t * 64 + lane;
                float4 c4 = xb4[m];
                float cs = c4.x * c4.x + c4.y * c4.y + c4.z * c4.z;
                float d = qs[qi] + cs
                        - 2.0f * (qx[qi] * c4.x + qy[qi] * c4.y + qz[qi] * c4.z);
                if (d < eh[15]) {
                    eh[15] = d; ei[15] = m;
                    #pragma unroll
                    for (int j = 15; j >= 1; --j)
                        if (eh[j] < eh[j - 1]) {
                            float td = eh[j]; eh[j] = eh[j - 1]; eh[j - 1] = td;
                            int ti = ei[j]; ei[j] = ei[j - 1]; ei[j - 1] = ti;
                        }
                }
            }
            #pragma unroll 1
            for (int r = 0; r < KNN; ++r) {
                float d = eh[0]; int i = ei[0];
                #pragma unroll
                for (int s = 1; s < 64; s <<= 1) {
                    float d2 = __shfl_xor(d, s); int i2 = __shfl_xor(i, s);
                    if (d2 < d || (d2 == d && i2 < i)) { d = d2; i = i2; }
                }
                if (lane == r) mynb = i;
                if (ei[0] == i) {
                    #pragma unroll
                    for (int j = 0; j < 15; ++j) { eh[j] = eh[j + 1]; ei[j] = ei[j + 1]; }
                    eh[15] = 3.4e38f; ei[15] = 0x7fffffff;
                }
            }
        }
        mynb = min(max(mynb, 0), NPTS - 1);
        if (lane < KNN) knnIdx[(size_t)(pbase + qi) * KNN + lane] = mynb;
    }
}

// ---------------------------------------------------------------------------
// main: MFMA per-neighbor MLPs consuming knnIdx (proven verbatim R12/R14/R15).
// ---------------------------------------------------------------------------
__global__ __launch_bounds__(256) void LocalTransformer_80513456931527_kernel(
    const float* __restrict__ xyzp, const float* __restrict__ features,
    const float* __restrict__ Wp1,  const float* __restrict__ bp1,
    const float* __restrict__ bp2,  const float* __restrict__ bt1,
    const float* __restrict__ bt2,
    const float* __restrict__ Wa,   const float* __restrict__ ba,
    const float* __restrict__ qw, const float* __restrict__ kw,
    const float* __restrict__ vw,
    const unsigned short* __restrict__ fragw,
    const int* __restrict__ knnIdx,
    float* __restrict__ out)
{
    __shared__ __align__(16) float sBounce[4][16 * 68 + 4];

    int tid = threadIdx.x, w = tid >> 6, lane = tid & 63;
    int p = blockIdx.x * 4 + w;
    int b = p >> 13;
    float* bb = sBounce[w];

    int quad = lane >> 4, l15 = lane & 15;
    int mynb = knnIdx[(size_t)p * KNN + l15];
    mynb = min(max(mynb, 0), NPTS - 1);
    int nb_a = mynb;
    int nbm[4];
    #pragma unroll
    for (int r = 0; r < 4; ++r) nbm[r] = __shfl(mynb, quad * 4 + r);

    const float4 xq4 = *(const float4*)(xyzp + (size_t)p * 4);
    const float4 xn4 = *(const float4*)(xyzp + ((size_t)b * NPTS + nb_a) * 4);
    float rel0 = xq4.x - xn4.x, rel1 = xq4.y - xn4.y;
    float rel2 = xq4.z - xn4.z, rel3 = xq4.w - xn4.w;

    bf8_t pe1f[2];
    #pragma unroll
    for (int s = 0; s < 2; ++s) {
        int hb = s * 32 + quad * 8;
        float W0[8], W1[8], W2[8], W3[8], Bb[8];
        *(float4*)&W0[0] = *(const float4*)(Wp1 +       hb);
        *(float4*)&W0[4] = *(const float4*)(Wp1 +       hb + 4);
        *(float4*)&W1[0] = *(const float4*)(Wp1 +  64 + hb);
        *(float4*)&W1[4] = *(const float4*)(Wp1 +  64 + hb + 4);
        *(float4*)&W2[0] = *(const float4*)(Wp1 + 128 + hb);
        *(float4*)&W2[4] = *(const float4*)(Wp1 + 128 + hb + 4);
        *(float4*)&W3[0] = *(const float4*)(Wp1 + 192 + hb);
        *(float4*)&W3[4] = *(const float4*)(Wp1 + 192 + hb + 4);
        *(float4*)&Bb[0] = *(const float4*)(bp1 + hb);
        *(float4*)&Bb[4] = *(const float4*)(bp1 + hb + 4);
        #pragma unroll
        for (int j = 0; j < 8; ++j) {
            float a = Bb[j] + rel0 * W0[j] + rel1 * W1[j]
                            + rel2 * W2[j] + rel3 * W3[j];
            pe1f[s][j] = (short)f2b(fmaxf(a, 0.f));
        }
    }

    const bf8_t* BW = (const bf8_t*)fragw;
    f4_t pe2c[4];
    #pragma unroll
    for (int t = 0; t < 4; ++t) {
        f4_t acc = {0.f, 0.f, 0.f, 0.f};
        acc = MFMA16(pe1f[0], BW[0 * 512 + (0 * 4 + t) * 64 + lane], acc);
        acc = MFMA16(pe1f[1], BW[0 * 512 + (1 * 4 + t) * 64 + lane], acc);
        float bias = bp2[t * 16 + l15];
        #pragma unroll
        for (int r = 0; r < 4; ++r) acc[r] += bias;
        pe2c[t] = acc;
    }

    f4_t ainc[4], vpec[4];
    #pragma unroll
    for (int t = 0; t < 4; ++t) {
        float qv = qw[(size_t)p * HDIM + t * 16 + l15];
        #pragma unroll
        for (int r = 0; r < 4; ++r) {
            size_t nbo = ((size_t)b * NPTS + nbm[r]) * HDIM + t * 16 + l15;
            ainc[t][r] = qv - kw[nbo] + pe2c[t][r];
            vpec[t][r] = vw[nbo] + pe2c[t][r];
        }
    }

    #pragma unroll
    for (int t = 0; t < 4; ++t)
        #pragma unroll
        for (int r = 0; r < 4; ++r)
            bb[(quad * 4 + r) * 68 + t * 16 + l15] = ainc[t][r];
    asm volatile("s_waitcnt lgkmcnt(0)" ::: "memory");
    bf8_t af[2];
    #pragma unroll
    for (int s = 0; s < 2; ++s) {
        float tmp[8];
        *(float4*)&tmp[0] = *(const float4*)&bb[l15 * 68 + s * 32 + quad * 8];
        *(float4*)&tmp[4] = *(const float4*)&bb[l15 * 68 + s * 32 + quad * 8 + 4];
        #pragma unroll
        for (int j = 0; j < 8; ++j) af[s][j] = (short)f2b(tmp[j]);
    }

    f4_t t1c[4];
    #pragma unroll
    for (int t = 0; t < 4; ++t) {
        f4_t acc = {0.f, 0.f, 0.f, 0.f};
        acc = MFMA16(af[0], BW[1 * 512 + (0 * 4 + t) * 64 + lane], acc);
        acc = MFMA16(af[1], BW[1 * 512 + (1 * 4 + t) * 64 + lane], acc);
        float bias = bt1[t * 16 + l15];
        #pragma unroll
        for (int r = 0; r < 4; ++r) t1c[t][r] = fmaxf(acc[r] + bias, 0.f);
    }

    asm volatile("s_waitcnt lgkmcnt(0)" ::: "memory");
    #pragma unroll
    for (int t = 0; t < 4; ++t)
        #pragma unroll
        for (int r = 0; r < 4; ++r)
            bb[(quad * 4 + r) * 68 + t * 16 + l15] = t1c[t][r];
    asm volatile("s_waitcnt lgkmcnt(0)" ::: "memory");
    bf8_t tf[2];
    #pragma unroll
    for (int s = 0; s < 2; ++s) {
        float tmp[8];
        *(float4*)&tmp[0] = *(const float4*)&bb[l15 * 68 + s * 32 + quad * 8];
        *(float4*)&tmp[4] = *(const float4*)&bb[l15 * 68 + s * 32 + quad * 8 + 4];
        #pragma unroll
        for (int j = 0; j < 8; ++j) tf[s][j] = (short)f2b(tmp[j]);
    }

    f4_t lgc[4];
    #pragma unroll
    for (int t = 0; t < 4; ++t) {
        f4_t acc = {0.f, 0.f, 0.f, 0.f};
        acc = MFMA16(tf[0], BW[2 * 512 + (0 * 4 + t) * 64 + lane], acc);
        acc = MFMA16(tf[1], BW[2 * 512 + (1 * 4 + t) * 64 + lane], acc);
        float bias = bt2[t * 16 + l15];
        #pragma unroll
        for (int r = 0; r < 4; ++r) lgc[t][r] = (acc[r] + bias) * 0.125f;
    }

    float res[4];
    #pragma unroll
    for (int t = 0; t < 4; ++t) {
        float m0 = fmaxf(fmaxf(lgc[t][0], lgc[t][1]), fmaxf(lgc[t][2], lgc[t][3]));
        m0 = fmaxf(m0, __shfl_xor(m0, 16));
        m0 = fmaxf(m0, __shfl_xor(m0, 32));
        float e0 = fast_exp(lgc[t][0] - m0), e1 = fast_exp(lgc[t][1] - m0);
        float e2 = fast_exp(lgc[t][2] - m0), e3 = fast_exp(lgc[t][3] - m0);
        float sl = e0 + e1 + e2 + e3;
        float rl = e0 * vpec[t][0] + e1 * vpec[t][1]
                 + e2 * vpec[t][2] + e3 * vpec[t][3];
        sl += __shfl_xor(sl, 16); sl += __shfl_xor(sl, 32);
        rl += __shfl_xor(rl, 16); rl += __shfl_xor(rl, 32);
        res[t] = rl / sl;
    }

    float rh = (quad == 0) ? res[0] : (quad == 1) ? res[1]
             : (quad == 2) ? res[2] : res[3];
    float f = features[(size_t)p * HDIM + lane];
    float o = ba[lane];
    #pragma unroll 8
    for (int c = 0; c < 64; ++c) o += __shfl(rh, c) * Wa[c * 64 + lane];
    out[(size_t)p * HDIM + lane] = o + f;
}

// ---------------------------------------------------------------------------
extern "C" void kernel_launch(void* const* d_in, const int* in_sizes, int n_in,
                              void* d_out, int out_size, void* d_ws, size_t ws_size,
                              hipStream_t stream)
{
    (void)in_sizes; (void)n_in; (void)out_size; (void)ws_size;
    const float* xyzp     = (const float*)d_in[0];
    const float* features = (const float*)d_in[1];
    const float* Wk  = (const float*)d_in[2];
    const float* bk  = (const float*)d_in[3];
    const float* Wq  = (const float*)d_in[4];
    const float* Wks = (const float*)d_in[5];
    const float* Wv  = (const float*)d_in[6];
    const float* Wp1 = (const float*)d_in[7];
    const float* bp1 = (const float*)d_in[8];
    const float* Wp2 = (const float*)d_in[9];
    const float* bp2 = (const float*)d_in[10];
    const float* Wt1 = (const float*)d_in[11];
    const float* bt1 = (const float*)d_in[12];
    const float* Wt2 = (const float*)d_in[13];
    const float* bt2 = (const float*)d_in[14];
    const float* Wa  = (const float*)d_in[15];
    const float* ba  = (const float*)d_in[16];
    float* out = (float*)d_out;
    char* ws = (char*)d_ws;

    float* qw = (float*)(ws + OFF_QW);
    float* kw = (float*)(ws + OFF_KW);
    float* vw = (float*)(ws + OFF_VW);
    unsigned short* fragw = (unsigned short*)(ws + OFF_FRAG);
    int* knnIdx = (int*)(ws + OFF_KNN);

    prefrag_kernel<<<48, 256, 0, stream>>>(Wp2, Wt1, Wt2, fragw);
    proj_kernel<<<(2 * NPTS) / 16, 1024, 0, stream>>>(
        features, Wk, bk, Wq, Wks, Wv, qw, kw, vw);
    knn2_kernel<<<(2 * NPTS) / 8, 256, 0, stream>>>(xyzp, knnIdx);
    LocalTransformer_80513456931527_kernel<<<(2 * NPTS) / 4, 256, 0, stream>>>(
        xyzp, features, Wp1, bp1, bp2, bt1, bt2, Wa, ba,
        qw, kw, vw, fragw, knnIdx, out);
}